// Round 4
// baseline (271.793 us; speedup 1.0000x reference)
//
#include <hip/hip_runtime.h>
#include <hip/hip_bf16.h>

typedef _Float16 f16x2 __attribute__((ext_vector_type(2)));
typedef _Float16 f16x8 __attribute__((ext_vector_type(8)));
typedef float    f32x4 __attribute__((ext_vector_type(4)));

#define IN_DIM   32
#define EDGE_DIM 16
#define HDIM     64
#define OUT_DIM  6
#define BN_EPS   1e-5f

// ============ fused setup: pack We (MFMA frags) | encode h0 | prep eaH+deg | bounds ============
__global__ __launch_bounds__(256) void k_setup(
    const float* __restrict__ We, uint4* __restrict__ WeB,
    const float* __restrict__ x, const float* __restrict__ Wx,
    const float* __restrict__ bx, float* __restrict__ h,
    const float* __restrict__ ea, _Float16* __restrict__ eaH,
    const int* __restrict__ dstI, int* __restrict__ degI,
    const int* __restrict__ batch, int* __restrict__ start,
    int N, int E, int G, int PACKB, int ENCB, int PREPB)
{
    __shared__ float w[2048];
    int bid = blockIdx.x;
    int t = threadIdx.x;

    if (bid < PACKB) {                       // ---- pack We: [layer][tile=h*4+o][lane<32] uint4
        int layer = bid / 32, chunk = bid % 32;
        int colbase = chunk * 128;
        #pragma unroll
        for (int i = 0; i < 8; ++i) {
            int idx = i * 256 + t;
            int k = idx >> 7, c = idx & 127;
            w[idx] = We[(size_t)layer * 65536 + k * 4096 + colbase + c];
        }
        __syncthreads();
        int tile = t >> 5, lane = t & 31;
        int kslot = lane >> 4, col = tile * 16 + (lane & 15);
        f16x8 v;
        #pragma unroll
        for (int j = 0; j < 8; ++j) v[j] = (_Float16)w[(kslot * 8 + j) * 128 + col];
        WeB[(size_t)layer * 8192 + (size_t)(chunk * 8 + tile) * 32 + lane] = __builtin_bit_cast(uint4, v);
        return;
    }
    bid -= PACKB;
    if (bid < ENCB) {                        // ---- encode: h0 = x @ Wx + bx
        int tid = bid * 256 + t;
        int n = tid >> 4, jq = tid & 15;
        if (n >= N) return;
        const float4* W4 = (const float4*)Wx;
        float4 acc = ((const float4*)bx)[jq];
        const float4* xv = (const float4*)(x + (size_t)n * IN_DIM);
        #pragma unroll
        for (int k4 = 0; k4 < 8; ++k4) {
            float4 xk = xv[k4];
            #pragma unroll
            for (int i = 0; i < 4; ++i) {
                float xs = (i == 0) ? xk.x : (i == 1) ? xk.y : (i == 2) ? xk.z : xk.w;
                float4 ww = W4[(k4 * 4 + i) * 16 + jq];
                acc.x += xs * ww.x; acc.y += xs * ww.y; acc.z += xs * ww.z; acc.w += xs * ww.w;
            }
        }
        ((float4*)h)[tid] = acc;
        return;
    }
    bid -= ENCB;
    if (bid < PREPB) {                       // ---- prep: eaH f16 convert + degree count
        int tid = bid * 256 + t;
        int E8 = E * 8;
        if (tid < E8) {
            float2 v = ((const float2*)ea)[tid];
            f16x2 r; r[0] = (_Float16)v.x; r[1] = (_Float16)v.y;
            ((f16x2*)eaH)[tid] = r;
        }
        if (tid < E) atomicAdd(&degI[dstI[tid]], 1);
        return;
    }
    // ---- bounds: start[g] via binary search (batch sorted)
    if (t <= G) {
        int lo = 0, hi = N;
        while (lo < hi) { int mid = (lo + hi) >> 1; if (batch[mid] < t) lo = mid + 1; else hi = mid; }
        start[t] = lo;
    }
}

// ============ CSR build: one-block prefix scan, then place ============
__global__ void k_scan(const int* __restrict__ degI, int* __restrict__ rowptr,
                       int* __restrict__ cursor, int N) {
    __shared__ int buf[256];
    __shared__ int carry;
    int t = threadIdx.x;
    if (t == 0) carry = 0;
    __syncthreads();
    for (int base = 0; base < N; base += 256) {
        int v = (base + t < N) ? degI[base + t] : 0;
        buf[t] = v;
        __syncthreads();
        for (int ofs = 1; ofs < 256; ofs <<= 1) {
            int xv = (t >= ofs) ? buf[t - ofs] : 0;
            __syncthreads();
            buf[t] += xv;
            __syncthreads();
        }
        int excl = buf[t] - v;
        int total = buf[255];
        if (base + t < N) {
            int rp = carry + excl;
            rowptr[base + t] = rp;
            cursor[base + t] = rp;
        }
        __syncthreads();
        if (t == 0) carry += total;
        __syncthreads();
    }
    if (t == 0) rowptr[N] = carry;
}

__global__ void k_place(const int* __restrict__ dstI, int* __restrict__ cursor,
                        int* __restrict__ eidx, int E) {
    int e = blockIdx.x * 256 + threadIdx.x;
    if (e < E) {
        int p = atomicAdd(&cursor[dstI[e]], 1);
        eidx[p] = e;
    }
}

// ============ fused edge MLP (MFMA) + weighted h-reduce -> per-edge msg partials ============
// Block: (edge-group of 64) x (h-half of 32). 4 waves: (gp = edge-half, oh = o-half).
// No atomics: plain stores to msgP[hhalf][E][64].
__global__ __launch_bounds__(256, 6) void k_edge(
    const uint4* __restrict__ eaH,      // [E][2] uint4
    const uint4* __restrict__ WeB,      // layer base: [256 tiles][32] uint4
    const float* __restrict__ be,       // layer base: [4096] = [h*64+o]
    const float* __restrict__ hin,      // [N][64]
    const int* __restrict__ srcI,
    float* __restrict__ msgP,           // [2][E][64]
    int E)
{
    __shared__ float hsT[32][68];       // [h_local][edge_local]; stride 68: 2-way-free writes
    __shared__ float beL[2048];
    const int t = threadIdx.x;
    const int l = t & 63;
    const int w = t >> 6;
    const int eg = blockIdx.x >> 1;
    const int hhalf = blockIdx.x & 1;
    const int eb = eg * 64;
    const int hbase = hhalf * 32;

    // ---- stage hsT: wave w stages rows w*8..w*8+7 for all 64 edges (conflict-free) ----
    {
        int egc = min(eb + l, E - 1);
        int s = srcI[egc];
        const float4* hp = (const float4*)(hin + (size_t)s * HDIM + hbase + w * 8);
        float4 a = hp[0], b = hp[1];
        hsT[w*8+0][l] = a.x; hsT[w*8+1][l] = a.y; hsT[w*8+2][l] = a.z; hsT[w*8+3][l] = a.w;
        hsT[w*8+4][l] = b.x; hsT[w*8+5][l] = b.y; hsT[w*8+6][l] = b.z; hsT[w*8+7][l] = b.w;
    }
    // ---- stage beL: this h-half's 2048 biases ----
    {
        const float4* bg = (const float4*)(be + hbase * 64);
        float4* bs = (float4*)beL;
        bs[t] = bg[t];
        bs[256 + t] = bg[256 + t];
    }
    __syncthreads();

    const int gp  = w >> 1;              // edge half (32 edges)
    const int oh  = w & 1;               // o half (32 outs)
    const int ebw = eb + gp * 32;
    const int elw = gp * 32;
    const int g   = l >> 4;
    const int g4  = g * 4;
    const int c16 = l & 15;
    const int obase = oh * 32;

    // ---- A fragments: K=16 real (upper 16 k zero; annihilates B garbage lanes) ----
    f16x8 A0 = {}, A1 = {};
    if (g < 2) {
        int e0 = min(ebw + c16, E - 1);
        int e1 = min(ebw + 16 + c16, E - 1);
        A0 = __builtin_bit_cast(f16x8, eaH[(size_t)e0 * 2 + g]);
        A1 = __builtin_bit_cast(f16x8, eaH[(size_t)e1 * 2 + g]);
    }

    f32x4 acc00 = (f32x4)0.f, acc01 = (f32x4)0.f;   // edge-group 0, o-tiles 0/1
    f32x4 acc10 = (f32x4)0.f, acc11 = (f32x4)0.f;   // edge-group 1

    const uint4* Bbase = WeB + (size_t)(l & 31);
    uint4 Bv0 = Bbase[(size_t)(hbase * 4 + oh * 2 + 0) * 32];
    uint4 Bv1 = Bbase[(size_t)(hbase * 4 + oh * 2 + 1) * 32];

    for (int hh = 0; hh < 32; ++hh) {
        uint4 Bn0, Bn1;
        if (hh < 31) {
            const uint4* Bp = Bbase + (size_t)((hbase + hh + 1) * 4 + oh * 2) * 32;
            Bn0 = Bp[0]; Bn1 = Bp[32];
        }
        float4 p0 = *(const float4*)&hsT[hh][elw + g4];
        float4 p1 = *(const float4*)&hsT[hh][elw + 16 + g4];
        float bia0 = beL[hh * 64 + obase + c16];
        float bia1 = beL[hh * 64 + obase + 16 + c16];
        {
            f16x8 B = __builtin_bit_cast(f16x8, Bv0);
            f32x4 cin = {bia0, bia0, bia0, bia0};
            f32x4 z0 = __builtin_amdgcn_mfma_f32_16x16x32_f16(A0, B, cin, 0, 0, 0);
            f32x4 z1 = __builtin_amdgcn_mfma_f32_16x16x32_f16(A1, B, cin, 0, 0, 0);
            acc00[0] += fmaxf(z0[0], 0.f) * p0.x;
            acc00[1] += fmaxf(z0[1], 0.f) * p0.y;
            acc00[2] += fmaxf(z0[2], 0.f) * p0.z;
            acc00[3] += fmaxf(z0[3], 0.f) * p0.w;
            acc10[0] += fmaxf(z1[0], 0.f) * p1.x;
            acc10[1] += fmaxf(z1[1], 0.f) * p1.y;
            acc10[2] += fmaxf(z1[2], 0.f) * p1.z;
            acc10[3] += fmaxf(z1[3], 0.f) * p1.w;
        }
        {
            f16x8 B = __builtin_bit_cast(f16x8, Bv1);
            f32x4 cin = {bia1, bia1, bia1, bia1};
            f32x4 z0 = __builtin_amdgcn_mfma_f32_16x16x32_f16(A0, B, cin, 0, 0, 0);
            f32x4 z1 = __builtin_amdgcn_mfma_f32_16x16x32_f16(A1, B, cin, 0, 0, 0);
            acc01[0] += fmaxf(z0[0], 0.f) * p0.x;
            acc01[1] += fmaxf(z0[1], 0.f) * p0.y;
            acc01[2] += fmaxf(z0[2], 0.f) * p0.z;
            acc01[3] += fmaxf(z0[3], 0.f) * p0.w;
            acc11[0] += fmaxf(z1[0], 0.f) * p1.x;
            acc11[1] += fmaxf(z1[1], 0.f) * p1.y;
            acc11[2] += fmaxf(z1[2], 0.f) * p1.z;
            acc11[3] += fmaxf(z1[3], 0.f) * p1.w;
        }
        Bv0 = Bn0; Bv1 = Bn1;
    }

    // ---- plain stores: msgP[hhalf][e][obase + c16 (+16)] ----
    float* mw = msgP + (size_t)hhalf * E * 64;
    #pragma unroll
    for (int grp = 0; grp < 2; ++grp) {
        #pragma unroll
        for (int r = 0; r < 4; ++r) {
            int e = ebw + grp * 16 + g4 + r;
            if (e < E) {
                float v0 = grp == 0 ? acc00[r] : acc10[r];
                float v1 = grp == 0 ? acc01[r] : acc11[r];
                mw[(size_t)e * 64 + obase + c16]      = v0;
                mw[(size_t)e * 64 + obase + 16 + c16] = v1;
            }
        }
    }
}

// ============ node update: CSR gather-mean, root GEMV, relu, BN(eval), residual ============
__global__ void k_update(
    const float* __restrict__ msgP, const int* __restrict__ rowptr,
    const int* __restrict__ eidx,
    const float* __restrict__ hin, const float* __restrict__ Wroot,
    const float* __restrict__ broot, const float* __restrict__ gam,
    const float* __restrict__ bet, const float* __restrict__ rmean,
    const float* __restrict__ rvar, float* __restrict__ hout, int N, int E)
{
    int tid = blockIdx.x * 256 + threadIdx.x;   // N*16
    int n = tid >> 4, jq = tid & 15;
    if (n >= N) return;
    int r0 = rowptr[n], r1 = rowptr[n + 1];
    float4 s = make_float4(0.f, 0.f, 0.f, 0.f);
    const float4* m4 = (const float4*)msgP;
    for (int i = r0; i < r1; ++i) {
        int eid = eidx[i];
        float4 a = m4[(size_t)eid * 16 + jq];
        float4 b = m4[((size_t)E + eid) * 16 + jq];
        s.x += a.x + b.x; s.y += a.y + b.y; s.z += a.z + b.z; s.w += a.w + b.w;
    }
    float dinv = 1.0f / fmaxf((float)(r1 - r0), 1.0f);
    float4 acc = ((const float4*)broot)[jq];
    acc.x += s.x * dinv; acc.y += s.y * dinv; acc.z += s.z * dinv; acc.w += s.w * dinv;
    const float4* W4 = (const float4*)Wroot;
    const float4* hv = (const float4*)(hin + (size_t)n * HDIM);
    #pragma unroll
    for (int k4 = 0; k4 < 16; ++k4) {
        float4 hk = hv[k4];
        #pragma unroll
        for (int i = 0; i < 4; ++i) {
            float hsc = (i == 0) ? hk.x : (i == 1) ? hk.y : (i == 2) ? hk.z : hk.w;
            float4 ww = W4[(k4 * 4 + i) * 16 + jq];
            acc.x += hsc * ww.x; acc.y += hsc * ww.y; acc.z += hsc * ww.z; acc.w += hsc * ww.w;
        }
    }
    acc.x = fmaxf(acc.x, 0.f); acc.y = fmaxf(acc.y, 0.f);
    acc.z = fmaxf(acc.z, 0.f); acc.w = fmaxf(acc.w, 0.f);
    float4 g4 = ((const float4*)gam)[jq];
    float4 b4 = ((const float4*)bet)[jq];
    float4 mm4 = ((const float4*)rmean)[jq];
    float4 v4 = ((const float4*)rvar)[jq];
    float4 hres = ((const float4*)hin)[tid];
    float4 y;
    y.x = g4.x * (acc.x - mm4.x) * rsqrtf(v4.x + BN_EPS) + b4.x + hres.x;
    y.y = g4.y * (acc.y - mm4.y) * rsqrtf(v4.y + BN_EPS) + b4.y + hres.y;
    y.z = g4.z * (acc.z - mm4.z) * rsqrtf(v4.z + BN_EPS) + b4.z + hres.z;
    y.w = g4.w * (acc.w - mm4.w) * rsqrtf(v4.w + BN_EPS) + b4.w + hres.w;
    ((float4*)hout)[tid] = y;
}

// ============ fused pool (segment mean) + MLP head; no atomics ============
__global__ __launch_bounds__(256) void k_pool_head(
    const float* __restrict__ h, const int* __restrict__ start,
    const float* __restrict__ W1, const float* __restrict__ b1,
    const float* __restrict__ W2, const float* __restrict__ b2,
    float* __restrict__ out)
{
    __shared__ float sums[16][68];
    __shared__ float pl[HDIM];
    __shared__ float zl[HDIM];
    int g = blockIdx.x;
    int s0 = start[g], s1 = start[g + 1];
    int t = threadIdx.x, jq = t & 15, rp = t >> 4;
    float4 acc = make_float4(0.f, 0.f, 0.f, 0.f);
    for (int n = s0 + rp; n < s1; n += 16) {
        float4 v = ((const float4*)h)[(size_t)n * 16 + jq];
        acc.x += v.x; acc.y += v.y; acc.z += v.z; acc.w += v.w;
    }
    *(float4*)&sums[rp][jq * 4] = acc;
    __syncthreads();
    if (t < HDIM) {
        float a = 0.f;
        #pragma unroll
        for (int r = 0; r < 16; ++r) a += sums[r][t];
        float cnt = (float)(s1 - s0);
        pl[t] = a / fmaxf(cnt, 1.0f);
    }
    __syncthreads();
    if (t < HDIM) {
        float a = b1[t];
        #pragma unroll
        for (int k = 0; k < HDIM; ++k) a += pl[k] * W1[k * HDIM + t];
        zl[t] = fmaxf(a, 0.f);
    }
    __syncthreads();
    if (t < OUT_DIM) {
        float a = b2[t];
        #pragma unroll
        for (int k = 0; k < HDIM; ++k) a += zl[k] * W2[k * OUT_DIM + t];
        out[(size_t)g * OUT_DIM + t] = a;
    }
}

// ============ launch ============
extern "C" void kernel_launch(void* const* d_in, const int* in_sizes, int n_in,
                              void* d_out, int out_size, void* d_ws, size_t ws_size,
                              hipStream_t stream) {
    const float* x     = (const float*)d_in[0];
    const float* eattr = (const float*)d_in[1];
    const int*   src   = (const int*)d_in[2];
    const int*   dst   = (const int*)d_in[3];
    const int*   batch = (const int*)d_in[4];
    const float* Wx    = (const float*)d_in[5];
    const float* bx    = (const float*)d_in[6];
    const float* We    = (const float*)d_in[7];
    const float* be    = (const float*)d_in[8];
    const float* Wroot = (const float*)d_in[9];
    const float* broot = (const float*)d_in[10];
    const float* gam   = (const float*)d_in[11];
    const float* bet   = (const float*)d_in[12];
    const float* rmean = (const float*)d_in[13];
    const float* rvar  = (const float*)d_in[14];
    const float* W1    = (const float*)d_in[15];
    const float* b1    = (const float*)d_in[16];
    const float* W2    = (const float*)d_in[17];
    const float* b2    = (const float*)d_in[18];
    float* out = (float*)d_out;

    const int N = in_sizes[0] / IN_DIM;
    const int E = in_sizes[2];
    const int G = out_size / OUT_DIM;

    char* ws = (char*)d_ws;
    size_t off = 0;
    auto alloc = [&](size_t bytes) -> void* {
        void* p = ws + off;
        off = (off + bytes + 255) & ~(size_t)255;
        return p;
    };
    float*    h0     = (float*)alloc((size_t)N * HDIM * 4);
    float*    h1     = (float*)alloc((size_t)N * HDIM * 4);
    _Float16* eaH    = (_Float16*)alloc((size_t)E * 16 * 2);
    uint4*    WeB    = (uint4*)alloc((size_t)3 * 8192 * 16);
    int*      start  = (int*)alloc((size_t)(G + 1) * 4);
    int*      rowptr = (int*)alloc((size_t)(N + 1) * 4);
    int*      cursor = (int*)alloc((size_t)N * 4);
    int*      eidx   = (int*)alloc((size_t)E * 4);
    float*    msgP   = (float*)alloc((size_t)2 * E * HDIM * 4);
    int*      degI   = (int*)alloc((size_t)N * 4);       // memset region
    (void)ws_size; (void)n_in;

    hipMemsetAsync(degI, 0, (size_t)N * 4, stream);

    const int PACKB = 96;
    const int ENCB  = (N * 16 + 255) / 256;
    const int PREPB = (E * 8 + 255) / 256;
    k_setup<<<PACKB + ENCB + PREPB + 1, 256, 0, stream>>>(
        We, WeB, x, Wx, bx, h0, eattr, eaH, dst, degI, batch, start,
        N, E, G, PACKB, ENCB, PREPB);
    k_scan<<<1, 256, 0, stream>>>(degI, rowptr, cursor, N);
    k_place<<<(E + 255) / 256, 256, 0, stream>>>(dst, cursor, eidx, E);

    const float* hin = h0;
    float* hout = h1;
    const int edgeBlocks = ((E + 63) / 64) * 2;
    for (int l = 0; l < 3; ++l) {
        k_edge<<<edgeBlocks, 256, 0, stream>>>(
            (const uint4*)eaH, WeB + (size_t)l * 8192, be + (size_t)l * 4096,
            hin, src, msgP, E);
        k_update<<<(N * 16 + 255) / 256, 256, 0, stream>>>(
            msgP, rowptr, eidx, hin, Wroot + (size_t)l * 4096, broot + (size_t)l * 64,
            gam + (size_t)l * 64, bet + (size_t)l * 64, rmean + (size_t)l * 64,
            rvar + (size_t)l * 64, hout, N, E);
        float* tmp = hout; hout = (float*)hin; hin = tmp;
    }
    k_pool_head<<<G, 256, 0, stream>>>(hin, start, W1, b1, W2, b2, out);
}

// Round 5
// 191.930 us; speedup vs baseline: 1.4161x; 1.4161x over previous
//
#include <hip/hip_runtime.h>
#include <hip/hip_bf16.h>

typedef _Float16 f16x2 __attribute__((ext_vector_type(2)));
typedef _Float16 f16x8 __attribute__((ext_vector_type(8)));
typedef float    f32x4 __attribute__((ext_vector_type(4)));

#define IN_DIM   32
#define EDGE_DIM 16
#define HDIM     64
#define OUT_DIM  6
#define BN_EPS   1e-5f

// ============ fused setup: pack We (MFMA frags) | encode h0 | prep eaH+deg | bounds ============
__global__ __launch_bounds__(256) void k_setup(
    const float* __restrict__ We, uint4* __restrict__ WeB,
    const float* __restrict__ x, const float* __restrict__ Wx,
    const float* __restrict__ bx, float* __restrict__ h,
    const float* __restrict__ ea, _Float16* __restrict__ eaH,
    const int* __restrict__ dstI, int* __restrict__ degI,
    const int* __restrict__ batch, int* __restrict__ start,
    int N, int E, int G, int PACKB, int ENCB, int PREPB)
{
    __shared__ float w[2048];
    int bid = blockIdx.x;
    int t = threadIdx.x;

    if (bid < PACKB) {                       // ---- pack We: [layer][tile=h*4+o][lane<32] uint4
        int layer = bid / 32, chunk = bid % 32;
        int colbase = chunk * 128;
        #pragma unroll
        for (int i = 0; i < 8; ++i) {
            int idx = i * 256 + t;
            int k = idx >> 7, c = idx & 127;
            w[idx] = We[(size_t)layer * 65536 + k * 4096 + colbase + c];
        }
        __syncthreads();
        int tile = t >> 5, lane = t & 31;
        int kslot = lane >> 4, col = tile * 16 + (lane & 15);
        f16x8 v;
        #pragma unroll
        for (int j = 0; j < 8; ++j) v[j] = (_Float16)w[(kslot * 8 + j) * 128 + col];
        WeB[(size_t)layer * 8192 + (size_t)(chunk * 8 + tile) * 32 + lane] = __builtin_bit_cast(uint4, v);
        return;
    }
    bid -= PACKB;
    if (bid < ENCB) {                        // ---- encode: h0 = x @ Wx + bx
        int tid = bid * 256 + t;
        int n = tid >> 4, jq = tid & 15;
        if (n >= N) return;
        const float4* W4 = (const float4*)Wx;
        float4 acc = ((const float4*)bx)[jq];
        const float4* xv = (const float4*)(x + (size_t)n * IN_DIM);
        #pragma unroll
        for (int k4 = 0; k4 < 8; ++k4) {
            float4 xk = xv[k4];
            #pragma unroll
            for (int i = 0; i < 4; ++i) {
                float xs = (i == 0) ? xk.x : (i == 1) ? xk.y : (i == 2) ? xk.z : xk.w;
                float4 ww = W4[(k4 * 4 + i) * 16 + jq];
                acc.x += xs * ww.x; acc.y += xs * ww.y; acc.z += xs * ww.z; acc.w += xs * ww.w;
            }
        }
        ((float4*)h)[tid] = acc;
        return;
    }
    bid -= ENCB;
    if (bid < PREPB) {                       // ---- prep: eaH f16 convert + degree count
        int tid = bid * 256 + t;
        int E8 = E * 8;
        if (tid < E8) {
            float2 v = ((const float2*)ea)[tid];
            f16x2 r; r[0] = (_Float16)v.x; r[1] = (_Float16)v.y;
            ((f16x2*)eaH)[tid] = r;
        }
        if (tid < E) atomicAdd(&degI[dstI[tid]], 1);
        return;
    }
    // ---- bounds: start[g] via binary search (batch sorted)
    if (t <= G) {
        int lo = 0, hi = N;
        while (lo < hi) { int mid = (lo + hi) >> 1; if (batch[mid] < t) lo = mid + 1; else hi = mid; }
        start[t] = lo;
    }
}

// ============ CSR build: parallel 3-stage scan, then place ============
__global__ void k_scan_local(const int* __restrict__ degI, int* __restrict__ rowptr,
                             int* __restrict__ partials, int N) {
    __shared__ int buf[256];
    int b = blockIdx.x, t = threadIdx.x;
    int i = b * 256 + t;
    int v = (i < N) ? degI[i] : 0;
    buf[t] = v;
    __syncthreads();
    #pragma unroll
    for (int ofs = 1; ofs < 256; ofs <<= 1) {
        int xv = (t >= ofs) ? buf[t - ofs] : 0;
        __syncthreads();
        buf[t] += xv;
        __syncthreads();
    }
    if (i < N) rowptr[i] = buf[t] - v;          // local exclusive
    if (t == 255) partials[b] = buf[255];       // block total
}

__global__ void k_scan_top(int* __restrict__ partials, int nb) {
    __shared__ int buf[256];
    int t = threadIdx.x;
    int v = (t < nb) ? partials[t] : 0;
    buf[t] = v;
    __syncthreads();
    #pragma unroll
    for (int ofs = 1; ofs < 256; ofs <<= 1) {
        int xv = (t >= ofs) ? buf[t - ofs] : 0;
        __syncthreads();
        buf[t] += xv;
        __syncthreads();
    }
    if (t < nb) partials[t] = buf[t] - v;       // exclusive block offsets
    if (t == 0) partials[nb] = buf[255];        // grand total
}

__global__ void k_scan_add(int* __restrict__ rowptr, int* __restrict__ cursor,
                           const int* __restrict__ partials, int N, int nb) {
    int i = blockIdx.x * 256 + threadIdx.x;
    if (i < N) {
        int r = rowptr[i] + partials[blockIdx.x];
        rowptr[i] = r;
        cursor[i] = r;
    }
    if (i == 0) rowptr[N] = partials[nb];
}

__global__ void k_place(const int* __restrict__ dstI, int* __restrict__ cursor,
                        int* __restrict__ eidx, int E) {
    int e = blockIdx.x * 256 + threadIdx.x;
    if (e < E) {
        int p = atomicAdd(&cursor[dstI[e]], 1);
        eidx[p] = e;
    }
}

// ============ fused edge MLP (MFMA) + weighted h-reduce -> per-edge msg partials ============
// Block: (edge-group of 64) x (h-half of 32). 4 waves: (gp = edge-half, oh = o-half).
// No atomics: plain stores to msgP[hhalf][E][64].
__global__ __launch_bounds__(256, 6) void k_edge(
    const uint4* __restrict__ eaH,      // [E][2] uint4
    const uint4* __restrict__ WeB,      // layer base: [256 tiles][32] uint4
    const float* __restrict__ be,       // layer base: [4096] = [h*64+o]
    const float* __restrict__ hin,      // [N][64]
    const int* __restrict__ srcI,
    float* __restrict__ msgP,           // [2][E][64]
    int E)
{
    __shared__ float hsT[32][68];       // [h_local][edge_local]
    __shared__ float beL[2048];
    const int t = threadIdx.x;
    const int l = t & 63;
    const int w = t >> 6;
    const int eg = blockIdx.x >> 1;
    const int hhalf = blockIdx.x & 1;
    const int eb = eg * 64;
    const int hbase = hhalf * 32;

    // ---- stage hsT: wave w stages rows w*8..w*8+7 for all 64 edges ----
    {
        int egc = min(eb + l, E - 1);
        int s = srcI[egc];
        const float4* hp = (const float4*)(hin + (size_t)s * HDIM + hbase + w * 8);
        float4 a = hp[0], b = hp[1];
        hsT[w*8+0][l] = a.x; hsT[w*8+1][l] = a.y; hsT[w*8+2][l] = a.z; hsT[w*8+3][l] = a.w;
        hsT[w*8+4][l] = b.x; hsT[w*8+5][l] = b.y; hsT[w*8+6][l] = b.z; hsT[w*8+7][l] = b.w;
    }
    // ---- stage beL ----
    {
        const float4* bg = (const float4*)(be + hbase * 64);
        float4* bs = (float4*)beL;
        bs[t] = bg[t];
        bs[256 + t] = bg[256 + t];
    }
    __syncthreads();

    const int gp  = w >> 1;
    const int oh  = w & 1;
    const int ebw = eb + gp * 32;
    const int elw = gp * 32;
    const int g   = l >> 4;
    const int g4  = g * 4;
    const int c16 = l & 15;
    const int obase = oh * 32;

    // ---- A fragments: K=16 real (upper 16 k zero) ----
    f16x8 A0 = {}, A1 = {};
    if (g < 2) {
        int e0 = min(ebw + c16, E - 1);
        int e1 = min(ebw + 16 + c16, E - 1);
        A0 = __builtin_bit_cast(f16x8, eaH[(size_t)e0 * 2 + g]);
        A1 = __builtin_bit_cast(f16x8, eaH[(size_t)e1 * 2 + g]);
    }

    f32x4 acc00 = (f32x4)0.f, acc01 = (f32x4)0.f;
    f32x4 acc10 = (f32x4)0.f, acc11 = (f32x4)0.f;

    const uint4* Bbase = WeB + (size_t)(l & 31);
    uint4 Bv0 = Bbase[(size_t)(hbase * 4 + oh * 2 + 0) * 32];
    uint4 Bv1 = Bbase[(size_t)(hbase * 4 + oh * 2 + 1) * 32];

    for (int hh = 0; hh < 32; ++hh) {
        uint4 Bn0, Bn1;
        if (hh < 31) {
            const uint4* Bp = Bbase + (size_t)((hbase + hh + 1) * 4 + oh * 2) * 32;
            Bn0 = Bp[0]; Bn1 = Bp[32];
        }
        float4 p0 = *(const float4*)&hsT[hh][elw + g4];
        float4 p1 = *(const float4*)&hsT[hh][elw + 16 + g4];
        float bia0 = beL[hh * 64 + obase + c16];
        float bia1 = beL[hh * 64 + obase + 16 + c16];
        {
            f16x8 B = __builtin_bit_cast(f16x8, Bv0);
            f32x4 cin = {bia0, bia0, bia0, bia0};
            f32x4 z0 = __builtin_amdgcn_mfma_f32_16x16x32_f16(A0, B, cin, 0, 0, 0);
            f32x4 z1 = __builtin_amdgcn_mfma_f32_16x16x32_f16(A1, B, cin, 0, 0, 0);
            acc00[0] += fmaxf(z0[0], 0.f) * p0.x;
            acc00[1] += fmaxf(z0[1], 0.f) * p0.y;
            acc00[2] += fmaxf(z0[2], 0.f) * p0.z;
            acc00[3] += fmaxf(z0[3], 0.f) * p0.w;
            acc10[0] += fmaxf(z1[0], 0.f) * p1.x;
            acc10[1] += fmaxf(z1[1], 0.f) * p1.y;
            acc10[2] += fmaxf(z1[2], 0.f) * p1.z;
            acc10[3] += fmaxf(z1[3], 0.f) * p1.w;
        }
        {
            f16x8 B = __builtin_bit_cast(f16x8, Bv1);
            f32x4 cin = {bia1, bia1, bia1, bia1};
            f32x4 z0 = __builtin_amdgcn_mfma_f32_16x16x32_f16(A0, B, cin, 0, 0, 0);
            f32x4 z1 = __builtin_amdgcn_mfma_f32_16x16x32_f16(A1, B, cin, 0, 0, 0);
            acc01[0] += fmaxf(z0[0], 0.f) * p0.x;
            acc01[1] += fmaxf(z0[1], 0.f) * p0.y;
            acc01[2] += fmaxf(z0[2], 0.f) * p0.z;
            acc01[3] += fmaxf(z0[3], 0.f) * p0.w;
            acc11[0] += fmaxf(z1[0], 0.f) * p1.x;
            acc11[1] += fmaxf(z1[1], 0.f) * p1.y;
            acc11[2] += fmaxf(z1[2], 0.f) * p1.z;
            acc11[3] += fmaxf(z1[3], 0.f) * p1.w;
        }
        Bv0 = Bn0; Bv1 = Bn1;
    }

    // ---- plain stores ----
    float* mw = msgP + (size_t)hhalf * E * 64;
    #pragma unroll
    for (int grp = 0; grp < 2; ++grp) {
        #pragma unroll
        for (int r = 0; r < 4; ++r) {
            int e = ebw + grp * 16 + g4 + r;
            if (e < E) {
                float v0 = grp == 0 ? acc00[r] : acc10[r];
                float v1 = grp == 0 ? acc01[r] : acc11[r];
                mw[(size_t)e * 64 + obase + c16]      = v0;
                mw[(size_t)e * 64 + obase + 16 + c16] = v1;
            }
        }
    }
}

// ============ node update: CSR gather-mean, root GEMV, relu, BN(eval), residual ============
__global__ void k_update(
    const float* __restrict__ msgP, const int* __restrict__ rowptr,
    const int* __restrict__ eidx,
    const float* __restrict__ hin, const float* __restrict__ Wroot,
    const float* __restrict__ broot, const float* __restrict__ gam,
    const float* __restrict__ bet, const float* __restrict__ rmean,
    const float* __restrict__ rvar, float* __restrict__ hout, int N, int E)
{
    int tid = blockIdx.x * 256 + threadIdx.x;   // N*16
    int n = tid >> 4, jq = tid & 15;
    if (n >= N) return;
    int r0 = rowptr[n], r1 = rowptr[n + 1];
    float4 s = make_float4(0.f, 0.f, 0.f, 0.f);
    const float4* m4 = (const float4*)msgP;
    for (int i = r0; i < r1; ++i) {
        int eid = eidx[i];
        float4 a = m4[(size_t)eid * 16 + jq];
        float4 b = m4[((size_t)E + eid) * 16 + jq];
        s.x += a.x + b.x; s.y += a.y + b.y; s.z += a.z + b.z; s.w += a.w + b.w;
    }
    float dinv = 1.0f / fmaxf((float)(r1 - r0), 1.0f);
    float4 acc = ((const float4*)broot)[jq];
    acc.x += s.x * dinv; acc.y += s.y * dinv; acc.z += s.z * dinv; acc.w += s.w * dinv;
    const float4* W4 = (const float4*)Wroot;
    const float4* hv = (const float4*)(hin + (size_t)n * HDIM);
    #pragma unroll
    for (int k4 = 0; k4 < 16; ++k4) {
        float4 hk = hv[k4];
        #pragma unroll
        for (int i = 0; i < 4; ++i) {
            float hsc = (i == 0) ? hk.x : (i == 1) ? hk.y : (i == 2) ? hk.z : hk.w;
            float4 ww = W4[(k4 * 4 + i) * 16 + jq];
            acc.x += hsc * ww.x; acc.y += hsc * ww.y; acc.z += hsc * ww.z; acc.w += hsc * ww.w;
        }
    }
    acc.x = fmaxf(acc.x, 0.f); acc.y = fmaxf(acc.y, 0.f);
    acc.z = fmaxf(acc.z, 0.f); acc.w = fmaxf(acc.w, 0.f);
    float4 g4 = ((const float4*)gam)[jq];
    float4 b4 = ((const float4*)bet)[jq];
    float4 mm4 = ((const float4*)rmean)[jq];
    float4 v4 = ((const float4*)rvar)[jq];
    float4 hres = ((const float4*)hin)[tid];
    float4 y;
    y.x = g4.x * (acc.x - mm4.x) * rsqrtf(v4.x + BN_EPS) + b4.x + hres.x;
    y.y = g4.y * (acc.y - mm4.y) * rsqrtf(v4.y + BN_EPS) + b4.y + hres.y;
    y.z = g4.z * (acc.z - mm4.z) * rsqrtf(v4.z + BN_EPS) + b4.z + hres.z;
    y.w = g4.w * (acc.w - mm4.w) * rsqrtf(v4.w + BN_EPS) + b4.w + hres.w;
    ((float4*)hout)[tid] = y;
}

// ============ fused pool (segment mean) + MLP head; no atomics ============
__global__ __launch_bounds__(256) void k_pool_head(
    const float* __restrict__ h, const int* __restrict__ start,
    const float* __restrict__ W1, const float* __restrict__ b1,
    const float* __restrict__ W2, const float* __restrict__ b2,
    float* __restrict__ out)
{
    __shared__ float sums[16][68];
    __shared__ float pl[HDIM];
    __shared__ float zl[HDIM];
    int g = blockIdx.x;
    int s0 = start[g], s1 = start[g + 1];
    int t = threadIdx.x, jq = t & 15, rp = t >> 4;
    float4 acc = make_float4(0.f, 0.f, 0.f, 0.f);
    for (int n = s0 + rp; n < s1; n += 16) {
        float4 v = ((const float4*)h)[(size_t)n * 16 + jq];
        acc.x += v.x; acc.y += v.y; acc.z += v.z; acc.w += v.w;
    }
    *(float4*)&sums[rp][jq * 4] = acc;
    __syncthreads();
    if (t < HDIM) {
        float a = 0.f;
        #pragma unroll
        for (int r = 0; r < 16; ++r) a += sums[r][t];
        float cnt = (float)(s1 - s0);
        pl[t] = a / fmaxf(cnt, 1.0f);
    }
    __syncthreads();
    if (t < HDIM) {
        float a = b1[t];
        #pragma unroll
        for (int k = 0; k < HDIM; ++k) a += pl[k] * W1[k * HDIM + t];
        zl[t] = fmaxf(a, 0.f);
    }
    __syncthreads();
    if (t < OUT_DIM) {
        float a = b2[t];
        #pragma unroll
        for (int k = 0; k < HDIM; ++k) a += zl[k] * W2[k * OUT_DIM + t];
        out[(size_t)g * OUT_DIM + t] = a;
    }
}

// ============ launch ============
extern "C" void kernel_launch(void* const* d_in, const int* in_sizes, int n_in,
                              void* d_out, int out_size, void* d_ws, size_t ws_size,
                              hipStream_t stream) {
    const float* x     = (const float*)d_in[0];
    const float* eattr = (const float*)d_in[1];
    const int*   src   = (const int*)d_in[2];
    const int*   dst   = (const int*)d_in[3];
    const int*   batch = (const int*)d_in[4];
    const float* Wx    = (const float*)d_in[5];
    const float* bx    = (const float*)d_in[6];
    const float* We    = (const float*)d_in[7];
    const float* be    = (const float*)d_in[8];
    const float* Wroot = (const float*)d_in[9];
    const float* broot = (const float*)d_in[10];
    const float* gam   = (const float*)d_in[11];
    const float* bet   = (const float*)d_in[12];
    const float* rmean = (const float*)d_in[13];
    const float* rvar  = (const float*)d_in[14];
    const float* W1    = (const float*)d_in[15];
    const float* b1    = (const float*)d_in[16];
    const float* W2    = (const float*)d_in[17];
    const float* b2    = (const float*)d_in[18];
    float* out = (float*)d_out;

    const int N = in_sizes[0] / IN_DIM;
    const int E = in_sizes[2];
    const int G = out_size / OUT_DIM;

    char* ws = (char*)d_ws;
    size_t off = 0;
    auto alloc = [&](size_t bytes) -> void* {
        void* p = ws + off;
        off = (off + bytes + 255) & ~(size_t)255;
        return p;
    };
    float*    h0      = (float*)alloc((size_t)N * HDIM * 4);
    float*    h1      = (float*)alloc((size_t)N * HDIM * 4);
    _Float16* eaH     = (_Float16*)alloc((size_t)E * 16 * 2);
    uint4*    WeB     = (uint4*)alloc((size_t)3 * 8192 * 16);
    int*      start   = (int*)alloc((size_t)(G + 1) * 4);
    int*      rowptr  = (int*)alloc((size_t)(N + 1) * 4);
    int*      cursor  = (int*)alloc((size_t)N * 4);
    int*      eidx    = (int*)alloc((size_t)E * 4);
    float*    msgP    = (float*)alloc((size_t)2 * E * HDIM * 4);
    int*      degI    = (int*)alloc((size_t)N * 4);       // memset region
    const int nb      = (N + 255) / 256;
    int*      partials= (int*)alloc((size_t)(nb + 1) * 4);
    (void)ws_size; (void)n_in;

    hipMemsetAsync(degI, 0, (size_t)N * 4, stream);

    const int PACKB = 96;
    const int ENCB  = (N * 16 + 255) / 256;
    const int PREPB = (E * 8 + 255) / 256;
    k_setup<<<PACKB + ENCB + PREPB + 1, 256, 0, stream>>>(
        We, WeB, x, Wx, bx, h0, eattr, eaH, dst, degI, batch, start,
        N, E, G, PACKB, ENCB, PREPB);
    k_scan_local<<<nb, 256, 0, stream>>>(degI, rowptr, partials, N);
    k_scan_top<<<1, 256, 0, stream>>>(partials, nb);
    k_scan_add<<<nb, 256, 0, stream>>>(rowptr, cursor, partials, N, nb);
    k_place<<<(E + 255) / 256, 256, 0, stream>>>(dst, cursor, eidx, E);

    const float* hin = h0;
    float* hout = h1;
    const int edgeBlocks = ((E + 63) / 64) * 2;
    for (int l = 0; l < 3; ++l) {
        k_edge<<<edgeBlocks, 256, 0, stream>>>(
            (const uint4*)eaH, WeB + (size_t)l * 8192, be + (size_t)l * 4096,
            hin, src, msgP, E);
        k_update<<<(N * 16 + 255) / 256, 256, 0, stream>>>(
            msgP, rowptr, eidx, hin, Wroot + (size_t)l * 4096, broot + (size_t)l * 64,
            gam + (size_t)l * 64, bet + (size_t)l * 64, rmean + (size_t)l * 64,
            rvar + (size_t)l * 64, hout, N, E);
        float* tmp = hout; hout = (float*)hin; hin = tmp;
    }
    k_pool_head<<<G, 256, 0, stream>>>(hin, start, W1, b1, W2, b2, out);
}